// Round 4
// baseline (160.199 us; speedup 1.0000x reference)
//
#include <hip/hip_runtime.h>
#include <cstdint>

constexpr int B  = 4;
constexpr int C  = 128;
constexpr int CM = 32;        // mid channels
constexpr int H  = 160;
constexpr int W  = 160;
constexpr int HW = H * W;     // 25600
constexpr int HP = H + 1;     // 161
constexpr int WP = W + 1;     // 161
constexpr int PLANE = HP * WP; // 25921
constexpr int TY = 16;         // rows per box tile
constexpr int NTILE = H / TY;  // 10
constexpr int K1B = 400;       // K1 grid size
constexpr int NB2 = B * NTILE; // 40 partials per out-channel

// ---------------- K1: 1x1 conv (wave = 8 outs x 256 pos) + partial stats ----------------
__global__ __launch_bounds__(256) void k_conv(
    const float* __restrict__ x, const float* __restrict__ w1,
    float* __restrict__ h, float* __restrict__ part1)
{
    __shared__ float wT[C * CM];   // wT[c*CM + o]
    int tid = threadIdx.x;
    for (int i = tid; i < C * CM; i += 256) {
        int o = i & (CM - 1), c = i >> 5;
        wT[i] = w1[o * C + c];
    }
    __syncthreads();

    int wave = tid >> 6, lane = tid & 63;
    int bid = blockIdx.x;                 // 400 blocks; 100 per batch image
    int b = bid / 100;
    int p = (bid % 100) * 256 + lane * 4; // float4 per lane
    const float* xb = x + (size_t)b * C * HW + p;

    float4 acc[8];
    #pragma unroll
    for (int j = 0; j < 8; ++j) acc[j] = make_float4(0.f, 0.f, 0.f, 0.f);

    const float* wbase = &wT[wave * 8];   // this wave's 8 output channels
    #pragma unroll 4
    for (int c = 0; c < C; ++c) {
        float4 xv = *reinterpret_cast<const float4*>(xb + (size_t)c * HW);
        const float4* wr = reinterpret_cast<const float4*>(wbase + c * CM);
        float4 wa = wr[0], wb = wr[1];
        float wv[8] = {wa.x, wa.y, wa.z, wa.w, wb.x, wb.y, wb.z, wb.w};
        #pragma unroll
        for (int j = 0; j < 8; ++j) {
            acc[j].x = fmaf(wv[j], xv.x, acc[j].x);
            acc[j].y = fmaf(wv[j], xv.y, acc[j].y);
            acc[j].z = fmaf(wv[j], xv.z, acc[j].z);
            acc[j].w = fmaf(wv[j], xv.w, acc[j].w);
        }
    }

    float* hb = h + ((size_t)(b * CM + wave * 8)) * HW + p;
    #pragma unroll
    for (int j = 0; j < 8; ++j) {
        *reinterpret_cast<float4*>(hb + (size_t)j * HW) = acc[j];
        float s  = acc[j].x + acc[j].y + acc[j].z + acc[j].w;
        float s2 = acc[j].x * acc[j].x + acc[j].y * acc[j].y
                 + acc[j].z * acc[j].z + acc[j].w * acc[j].w;
        #pragma unroll
        for (int off = 32; off > 0; off >>= 1) {
            s  += __shfl_down(s,  off);
            s2 += __shfl_down(s2, off);
        }
        if (lane == 0) {
            int o = wave * 8 + j;
            part1[(size_t)o * K1B + bid]        = s;   // row o      : sums
            part1[(size_t)(o + CM) * K1B + bid] = s2;  // row CM + o : sumsq
        }
    }
}

// ---------------- R1: deterministic reduction -> BN1 scale/shift ----------------
__global__ __launch_bounds__(256) void k_reduce1(
    const float* __restrict__ part1, const float* __restrict__ g1,
    const float* __restrict__ b1, float* __restrict__ sc1)
{
    __shared__ double pr[256];
    __shared__ double dsum[2 * CM];
    int t = threadIdx.x;
    int row = t >> 2, j = t & 3;        // 64 rows x 4 threads
    double acc = 0.0;
    for (int i = j; i < K1B; i += 4) acc += (double)part1[(size_t)row * K1B + i];
    pr[t] = acc;
    __syncthreads();
    if (j == 0) dsum[row] = pr[t] + pr[t + 1] + pr[t + 2] + pr[t + 3];
    __syncthreads();
    if (t < CM) {
        double n = (double)(B * HW);
        double mean = dsum[t] / n;
        double var  = dsum[CM + t] / n - mean * mean;
        float inv   = (float)(1.0 / sqrt(var + 1e-5));
        float scale = g1[t] * inv;
        sc1[t]      = scale;
        sc1[CM + t] = b1[t] - (float)mean * scale;
    }
}

// ------- K2: fused BN1+ReLU + row scan + col scan + II write (block per plane) -------
__global__ __launch_bounds__(256) void k_scan(
    const float* __restrict__ h, const float* __restrict__ sc1,
    float* __restrict__ II)
{
    __shared__ float buf[80 * W];   // half-plane of row-scanned values, 51200 B
    int tid = threadIdx.x;
    int wave = tid >> 6, lane = tid & 63;
    int plane = blockIdx.x;         // b*CM + cm
    int cm = plane & (CM - 1);

    float scale = sc1[cm];
    float shift = sc1[CM + cm];

    const float* hp = h + (size_t)plane * HW;
    float* op = II + (size_t)plane * PLANE;

    // top border row
    for (int e = tid; e < WP; e += 256) op[e] = 0.f;

    float run = 0.f;   // per-column accumulator (threads 1..160; thread 0 = border col)
    for (int half = 0; half < 2; ++half) {
        // phase 1: BN+ReLU + row inclusive scan into LDS (wave-per-row shuffle scan)
        for (int y = wave; y < 80; y += 4) {
            int gy = half * 80 + y;
            const float* hr = hp + (size_t)gy * W;
            float carry = 0.f;
            #pragma unroll
            for (int x0 = 0; x0 < W; x0 += 64) {
                int xx = x0 + lane;
                float v = (xx < W) ? fmaxf(fmaf(scale, hr[xx], shift), 0.f) : 0.f;
                #pragma unroll
                for (int off = 1; off < 64; off <<= 1) {
                    float t = __shfl_up(v, off);
                    if (lane >= off) v += t;
                }
                v += carry;
                if (xx < W) buf[y * W + xx] = v;
                carry = __shfl(v, 63);
            }
        }
        __syncthreads();
        // phase 2: column scan + direct II write (thread = II column)
        if (tid <= W) {
            for (int r = 0; r < 80; ++r) {
                float v = 0.f;
                if (tid > 0) { run += buf[r * W + (tid - 1)]; v = run; }
                op[(size_t)(half * 80 + r + 1) * WP + tid] = v;
            }
        }
        __syncthreads();
    }
}

// ---------------- box tile machinery ----------------
struct BoxSmem {
    float D[TY][WP];      // row-interp difference rows
    int   ru0[2][TY];     // [0]=lo, [1]=hi row coords
    int   ru1[2][TY];
    float rua[2][TY];
    int   cv0[2][W];      // col coords ([0]=lo, [1]=hi)
    float cva[2][W];
};

__device__ inline void fill_D(BoxSmem& sm, const float* __restrict__ II,
    int tile, int k, int b,
    const float* __restrict__ xmin, const float* __restrict__ xmax,
    const float* __restrict__ ymin, const float* __restrict__ ymax)
{
    int tid = threadIdx.x;
    if (tid < 2 * TY) {
        int side = tid / TY, ty = tid % TY;
        float off = side ? (xmax[k] + 1.f) : xmin[k];
        float u = fminf(fmaxf((float)(tile * TY + ty) + off, 0.f), 160.f);
        float uf = floorf(u);
        int i0 = (int)uf;
        sm.ru0[side][ty] = i0;
        sm.ru1[side][ty] = min(i0 + 1, 160);
        sm.rua[side][ty] = u - uf;
    }
    for (int e = tid; e < 2 * W; e += 256) {
        int side = e / W, xx = e % W;
        float off = side ? (ymax[k] + 1.f) : ymin[k];
        float v = fminf(fmaxf((float)xx + off, 0.f), 160.f);
        float vf = floorf(v);
        sm.cv0[side][xx] = (int)vf;
        sm.cva[side][xx] = v - vf;
    }
    __syncthreads();

    const float* P = II + (size_t)(b * CM + (k >> 2)) * PLANE;
    for (int e = tid; e < TY * WP; e += 256) {
        int ty = e / WP, v = e % WP;
        float al = sm.rua[0][ty], ah = sm.rua[1][ty];
        float lo = P[(size_t)sm.ru0[0][ty] * WP + v] * (1.f - al)
                 + P[(size_t)sm.ru1[0][ty] * WP + v] * al;
        float hi = P[(size_t)sm.ru0[1][ty] * WP + v] * (1.f - ah)
                 + P[(size_t)sm.ru1[1][ty] * WP + v] * ah;
        sm.D[ty][v] = hi - lo;
    }
    __syncthreads();
}

__device__ inline float eval_D(const BoxSmem& sm, int ty, int xx)
{
    int   l0 = sm.cv0[0][xx];
    float la = sm.cva[0][xx];
    int   l1 = min(l0 + 1, 160);
    int   h0 = sm.cv0[1][xx];
    float ha = sm.cva[1][xx];
    int   h1 = min(h0 + 1, 160);
    const float* Dr = sm.D[ty];
    return (Dr[h0] * (1.f - ha) + Dr[h1] * ha)
         - (Dr[l0] * (1.f - la) + Dr[l1] * la);
}

// ---------------- K4: box conv -> BN2 partial stats ----------------
__global__ __launch_bounds__(256) void k_box_part(
    const float* __restrict__ II,
    const float* __restrict__ xmin, const float* __restrict__ xmax,
    const float* __restrict__ ymin, const float* __restrict__ ymax,
    float* __restrict__ part2)
{
    __shared__ BoxSmem sm;
    __shared__ float red[4][2];
    int tile = blockIdx.x, k = blockIdx.y, b = blockIdx.z;
    fill_D(sm, II, tile, k, b, xmin, xmax, ymin, ymax);

    float s = 0.f, s2 = 0.f;
    for (int o = threadIdx.x; o < TY * W; o += 256) {
        int ty = o / W, xx = o % W;
        float v = eval_D(sm, ty, xx);
        s  += v;
        s2 += v * v;
    }
    #pragma unroll
    for (int off = 32; off > 0; off >>= 1) {
        s  += __shfl_down(s,  off);
        s2 += __shfl_down(s2, off);
    }
    int wave = threadIdx.x >> 6, lane = threadIdx.x & 63;
    if (lane == 0) { red[wave][0] = s; red[wave][1] = s2; }
    __syncthreads();
    if (threadIdx.x == 0) {
        int idx = b * NTILE + tile;     // 0..39
        part2[(size_t)k * NB2 + idx]       = red[0][0] + red[1][0] + red[2][0] + red[3][0];
        part2[(size_t)(C + k) * NB2 + idx] = red[0][1] + red[1][1] + red[2][1] + red[3][1];
    }
}

// ---------------- R2: deterministic reduction -> BN2 scale/shift ----------------
__global__ __launch_bounds__(256) void k_reduce2(
    const float* __restrict__ part2, const float* __restrict__ g2,
    const float* __restrict__ b2, float* __restrict__ sc2)
{
    __shared__ double dsum[2 * C];
    int t = threadIdx.x;                 // 256 rows, one per thread
    double acc = 0.0;
    for (int i = 0; i < NB2; ++i) acc += (double)part2[(size_t)t * NB2 + i];
    dsum[t] = acc;
    __syncthreads();
    if (t < C) {
        double n = (double)(B * HW);
        double mean = dsum[t] / n;
        double var  = dsum[C + t] / n - mean * mean;
        float inv   = (float)(1.0 / sqrt(var + 1e-5));
        float scale = g2[t] * inv;
        sc2[t]     = scale;
        sc2[C + t] = b2[t] - (float)mean * scale;
    }
}

// ---------------- K5: box conv again, BN2, relu(x + h) ----------------
__global__ __launch_bounds__(256) void k_box_final(
    const float* __restrict__ II, const float* __restrict__ x,
    const float* __restrict__ xmin, const float* __restrict__ xmax,
    const float* __restrict__ ymin, const float* __restrict__ ymax,
    const float* __restrict__ sc2, float* __restrict__ out)
{
    __shared__ BoxSmem sm;
    int tile = blockIdx.x, k = blockIdx.y, b = blockIdx.z;
    fill_D(sm, II, tile, k, b, xmin, xmax, ymin, ymax);

    float scale = sc2[k], shift = sc2[C + k];
    size_t base = ((size_t)(b * C + k)) * HW + (size_t)tile * TY * W;
    for (int o = threadIdx.x; o < TY * W; o += 256) {
        int ty = o / W, xx = o % W;
        float v = eval_D(sm, ty, xx);
        size_t idx = base + (size_t)ty * W + xx;
        out[idx] = fmaxf(x[idx] + fmaf(scale, v, shift), 0.f);
    }
}

// ---------------- launch ----------------
extern "C" void kernel_launch(void* const* d_in, const int* in_sizes, int n_in,
                              void* d_out, int out_size, void* d_ws, size_t ws_size,
                              hipStream_t stream)
{
    const float* x    = (const float*)d_in[0];
    const float* w1   = (const float*)d_in[1];
    const float* g1   = (const float*)d_in[2];
    const float* b1   = (const float*)d_in[3];
    const float* xmin = (const float*)d_in[4];
    const float* xmax = (const float*)d_in[5];
    const float* ymin = (const float*)d_in[6];
    const float* ymax = (const float*)d_in[7];
    const float* g2   = (const float*)d_in[8];
    const float* b2   = (const float*)d_in[9];
    float* out = (float*)d_out;

    // ws layout (26.4 MB, same footprint as before):
    //   [0,256)      sc1: BN1 scale[32] | shift[32]
    //   [256,1280)   sc2: BN2 scale[128]| shift[128]
    //   [4096, +13107200)  h   (B*CM*HW floats)
    //   [+13107200, end)   II  (B*CM*PLANE floats)
    // part1 (64*400 floats = 102 KB) aliases the start of II: written by k_conv,
    //   consumed by k_reduce1, both BEFORE k_scan writes II.
    // part2 (256*40 floats = 41 KB) aliases the start of h: h is dead after k_scan.
    char* ws = (char*)d_ws;
    float* sc1 = (float*)ws;
    float* sc2 = (float*)(ws + 256);
    float* h   = (float*)(ws + 4096);
    float* II  = (float*)(ws + 4096 + (size_t)B * CM * HW * sizeof(float));
    float* part1 = II;
    float* part2 = h;

    k_conv     <<<dim3(K1B), 256, 0, stream>>>(x, w1, h, part1);
    k_reduce1  <<<dim3(1), 256, 0, stream>>>(part1, g1, b1, sc1);
    k_scan     <<<dim3(B * CM), 256, 0, stream>>>(h, sc1, II);
    k_box_part <<<dim3(NTILE, C, B), 256, 0, stream>>>(II, xmin, xmax, ymin, ymax, part2);
    k_reduce2  <<<dim3(1), 256, 0, stream>>>(part2, g2, b2, sc2);
    k_box_final<<<dim3(NTILE, C, B), 256, 0, stream>>>(II, x, xmin, xmax, ymin, ymax,
                                                       sc2, out);
}

// Round 5
// 144.242 us; speedup vs baseline: 1.1106x; 1.1106x over previous
//
#include <hip/hip_runtime.h>
#include <cstdint>

constexpr int B  = 4;
constexpr int C  = 128;
constexpr int CM = 32;        // mid channels
constexpr int H  = 160;
constexpr int W  = 160;
constexpr int HW = H * W;     // 25600
constexpr int HP = H + 1;     // 161
constexpr int WP = W + 1;     // 161
constexpr int PLANE = HP * WP; // 25921
constexpr int TY = 16;         // rows per box tile
constexpr int NTILE = H / TY;  // 10
constexpr int K1B = 800;       // K1 grid size
constexpr int NB2 = B * NTILE; // 40 partials per out-channel
constexpr int QR = 40;         // rows per scan quarter

// ---------------- K1: 1x1 conv (wave = 8 outs x 128 pos, float2/lane) ----------------
__global__ __launch_bounds__(256) void k_conv(
    const float* __restrict__ x, const float* __restrict__ w1,
    float* __restrict__ h, float* __restrict__ part1)
{
    __shared__ float wT[C * CM];   // wT[c*CM + o]
    int tid = threadIdx.x;
    for (int i = tid; i < C * CM; i += 256) {
        int o = i & (CM - 1), c = i >> 5;
        wT[i] = w1[o * C + c];
    }
    __syncthreads();

    int wave = tid >> 6, lane = tid & 63;
    int bid = blockIdx.x;                 // 800 blocks; 200 per batch image
    int b = bid / 200;
    int p = (bid % 200) * 128 + lane * 2; // float2 per lane
    const float* xb = x + (size_t)b * C * HW + p;

    float2 acc[8];
    #pragma unroll
    for (int j = 0; j < 8; ++j) acc[j] = make_float2(0.f, 0.f);

    const float* wbase = &wT[wave * 8];   // this wave's 8 output channels
    #pragma unroll 4
    for (int c = 0; c < C; ++c) {
        float2 xv = *reinterpret_cast<const float2*>(xb + (size_t)c * HW);
        const float4* wr = reinterpret_cast<const float4*>(wbase + c * CM);
        float4 wa = wr[0], wb4 = wr[1];
        float wv[8] = {wa.x, wa.y, wa.z, wa.w, wb4.x, wb4.y, wb4.z, wb4.w};
        #pragma unroll
        for (int j = 0; j < 8; ++j) {
            acc[j].x = fmaf(wv[j], xv.x, acc[j].x);
            acc[j].y = fmaf(wv[j], xv.y, acc[j].y);
        }
    }

    float* hb = h + ((size_t)(b * CM + wave * 8)) * HW + p;
    #pragma unroll
    for (int j = 0; j < 8; ++j) {
        *reinterpret_cast<float2*>(hb + (size_t)j * HW) = acc[j];
        float s  = acc[j].x + acc[j].y;
        float s2 = acc[j].x * acc[j].x + acc[j].y * acc[j].y;
        #pragma unroll
        for (int off = 32; off > 0; off >>= 1) {
            s  += __shfl_down(s,  off);
            s2 += __shfl_down(s2, off);
        }
        if (lane == 0) {
            int o = wave * 8 + j;
            part1[(size_t)o * K1B + bid]        = s;   // row o      : sums
            part1[(size_t)(o + CM) * K1B + bid] = s2;  // row CM + o : sumsq
        }
    }
}

// ---------------- R1: deterministic reduction -> BN1 scale/shift ----------------
__global__ __launch_bounds__(256) void k_reduce1(
    const float* __restrict__ part1, const float* __restrict__ g1,
    const float* __restrict__ b1, float* __restrict__ sc1)
{
    __shared__ double pr[256];
    __shared__ double dsum[2 * CM];
    int t = threadIdx.x;
    int row = t >> 2, j = t & 3;        // 64 rows x 4 threads
    double acc = 0.0;
    for (int i = j; i < K1B; i += 4) acc += (double)part1[(size_t)row * K1B + i];
    pr[t] = acc;
    __syncthreads();
    if (j == 0) dsum[row] = pr[t] + pr[t + 1] + pr[t + 2] + pr[t + 3];
    __syncthreads();
    if (t < CM) {
        double n = (double)(B * HW);
        double mean = dsum[t] / n;
        double var  = dsum[CM + t] / n - mean * mean;
        float inv   = (float)(1.0 / sqrt(var + 1e-5));
        float scale = g1[t] * inv;
        sc1[t]      = scale;
        sc1[CM + t] = b1[t] - (float)mean * scale;
    }
}

// ------- K2a: BN1+ReLU + row scan + LOCAL col scan per (plane, quarter) -------
__global__ __launch_bounds__(256) void k_scan_part(
    const float* __restrict__ h, const float* __restrict__ sc1,
    float* __restrict__ II)
{
    __shared__ float buf[QR * W];   // 40 row-scanned rows, 25600 B
    int tid = threadIdx.x;
    int wave = tid >> 6, lane = tid & 63;
    int blk = blockIdx.x;           // plane*4 + q
    int plane = blk >> 2, q = blk & 3;
    int cm = plane & (CM - 1);

    float scale = sc1[cm];
    float shift = sc1[CM + cm];

    const float* hp = h + (size_t)plane * HW + (size_t)q * QR * W;
    float* IIp = II + (size_t)plane * PLANE;

    // top border row (quarter 0 only) — independent of buf
    if (q == 0) {
        for (int e = tid; e < WP; e += 256) IIp[e] = 0.f;
    }

    // phase 1: BN+ReLU + row inclusive scan into LDS (wave-per-row shuffle scan)
    for (int y = wave; y < QR; y += 4) {
        const float* hr = hp + (size_t)y * W;
        float carry = 0.f;
        #pragma unroll
        for (int x0 = 0; x0 < W; x0 += 64) {
            int xx = x0 + lane;
            float v = (xx < W) ? fmaxf(fmaf(scale, hr[xx], shift), 0.f) : 0.f;
            #pragma unroll
            for (int off = 1; off < 64; off <<= 1) {
                float t = __shfl_up(v, off);
                if (lane >= off) v += t;
            }
            v += carry;
            if (xx < W) buf[y * W + xx] = v;
            carry = __shfl(v, 63);
        }
    }
    __syncthreads();

    // phase 2: local column scan + write II rows q*40+1 .. q*40+40
    float* op = IIp + (size_t)(q * QR + 1) * WP;
    if (tid <= W) {
        float run = 0.f;
        #pragma unroll 4
        for (int r = 0; r < QR; ++r) {
            float v = 0.f;
            if (tid > 0) { run += buf[r * W + (tid - 1)]; v = run; }
            op[(size_t)r * WP + tid] = v;
        }
    }
}

// ------- K2b: add cross-quarter offsets (one block per plane) -------
__global__ __launch_bounds__(256) void k_scan_fix(float* __restrict__ II)
{
    __shared__ float off[3][WP];
    int tid = threadIdx.x;
    float* P = II + (size_t)blockIdx.x * PLANE;

    for (int v = tid; v < WP; v += 256) {
        float l0 = P[(size_t)40 * WP + v];    // local last rows (pre-fix)
        float l1 = P[(size_t)80 * WP + v];
        float l2 = P[(size_t)120 * WP + v];
        off[0][v] = l0;
        off[1][v] = l0 + l1;
        off[2][v] = l0 + l1 + l2;
    }
    __syncthreads();

    constexpr int total = 120 * WP;           // rows 41..160
    for (int e = tid; e < total; e += 256) {
        int r = 41 + e / WP;
        int v = e % WP;
        P[(size_t)r * WP + v] += off[(r - 41) / QR][v];
    }
}

// ---------------- box tile machinery ----------------
struct BoxSmem {
    float D[TY][WP];      // row-interp difference rows
    int   ru0[2][TY];     // [0]=lo, [1]=hi row coords
    int   ru1[2][TY];
    float rua[2][TY];
    int   cv0[2][W];      // col coords ([0]=lo, [1]=hi)
    float cva[2][W];
};

__device__ inline void fill_D(BoxSmem& sm, const float* __restrict__ II,
    int tile, int k, int b,
    const float* __restrict__ xmin, const float* __restrict__ xmax,
    const float* __restrict__ ymin, const float* __restrict__ ymax)
{
    int tid = threadIdx.x;
    if (tid < 2 * TY) {
        int side = tid / TY, ty = tid % TY;
        float off = side ? (xmax[k] + 1.f) : xmin[k];
        float u = fminf(fmaxf((float)(tile * TY + ty) + off, 0.f), 160.f);
        float uf = floorf(u);
        int i0 = (int)uf;
        sm.ru0[side][ty] = i0;
        sm.ru1[side][ty] = min(i0 + 1, 160);
        sm.rua[side][ty] = u - uf;
    }
    for (int e = tid; e < 2 * W; e += 256) {
        int side = e / W, xx = e % W;
        float off = side ? (ymax[k] + 1.f) : ymin[k];
        float v = fminf(fmaxf((float)xx + off, 0.f), 160.f);
        float vf = floorf(v);
        sm.cv0[side][xx] = (int)vf;
        sm.cva[side][xx] = v - vf;
    }
    __syncthreads();

    const float* P = II + (size_t)(b * CM + (k >> 2)) * PLANE;
    for (int e = tid; e < TY * WP; e += 256) {
        int ty = e / WP, v = e % WP;
        float al = sm.rua[0][ty], ah = sm.rua[1][ty];
        float lo = P[(size_t)sm.ru0[0][ty] * WP + v] * (1.f - al)
                 + P[(size_t)sm.ru1[0][ty] * WP + v] * al;
        float hi = P[(size_t)sm.ru0[1][ty] * WP + v] * (1.f - ah)
                 + P[(size_t)sm.ru1[1][ty] * WP + v] * ah;
        sm.D[ty][v] = hi - lo;
    }
    __syncthreads();
}

__device__ inline float eval_D(const BoxSmem& sm, int ty, int xx)
{
    int   l0 = sm.cv0[0][xx];
    float la = sm.cva[0][xx];
    int   l1 = min(l0 + 1, 160);
    int   h0 = sm.cv0[1][xx];
    float ha = sm.cva[1][xx];
    int   h1 = min(h0 + 1, 160);
    const float* Dr = sm.D[ty];
    return (Dr[h0] * (1.f - ha) + Dr[h1] * ha)
         - (Dr[l0] * (1.f - la) + Dr[l1] * la);
}

// ---------------- K4: box conv -> BN2 partial stats ----------------
__global__ __launch_bounds__(256) void k_box_part(
    const float* __restrict__ II,
    const float* __restrict__ xmin, const float* __restrict__ xmax,
    const float* __restrict__ ymin, const float* __restrict__ ymax,
    float* __restrict__ part2)
{
    __shared__ BoxSmem sm;
    __shared__ float red[4][2];
    int tile = blockIdx.x, k = blockIdx.y, b = blockIdx.z;
    fill_D(sm, II, tile, k, b, xmin, xmax, ymin, ymax);

    float s = 0.f, s2 = 0.f;
    for (int o = threadIdx.x; o < TY * W; o += 256) {
        int ty = o / W, xx = o % W;
        float v = eval_D(sm, ty, xx);
        s  += v;
        s2 += v * v;
    }
    #pragma unroll
    for (int off = 32; off > 0; off >>= 1) {
        s  += __shfl_down(s,  off);
        s2 += __shfl_down(s2, off);
    }
    int wave = threadIdx.x >> 6, lane = threadIdx.x & 63;
    if (lane == 0) { red[wave][0] = s; red[wave][1] = s2; }
    __syncthreads();
    if (threadIdx.x == 0) {
        int idx = b * NTILE + tile;     // 0..39
        part2[(size_t)k * NB2 + idx]       = red[0][0] + red[1][0] + red[2][0] + red[3][0];
        part2[(size_t)(C + k) * NB2 + idx] = red[0][1] + red[1][1] + red[2][1] + red[3][1];
    }
}

// ---------------- R2: deterministic reduction -> BN2 scale/shift ----------------
__global__ __launch_bounds__(256) void k_reduce2(
    const float* __restrict__ part2, const float* __restrict__ g2,
    const float* __restrict__ b2, float* __restrict__ sc2)
{
    __shared__ double dsum[2 * C];
    int t = threadIdx.x;                 // 256 rows, one per thread
    double acc = 0.0;
    for (int i = 0; i < NB2; ++i) acc += (double)part2[(size_t)t * NB2 + i];
    dsum[t] = acc;
    __syncthreads();
    if (t < C) {
        double n = (double)(B * HW);
        double mean = dsum[t] / n;
        double var  = dsum[C + t] / n - mean * mean;
        float inv   = (float)(1.0 / sqrt(var + 1e-5));
        float scale = g2[t] * inv;
        sc2[t]     = scale;
        sc2[C + t] = b2[t] - (float)mean * scale;
    }
}

// ---------------- K5: box conv again, BN2, relu(x + h) ----------------
__global__ __launch_bounds__(256) void k_box_final(
    const float* __restrict__ II, const float* __restrict__ x,
    const float* __restrict__ xmin, const float* __restrict__ xmax,
    const float* __restrict__ ymin, const float* __restrict__ ymax,
    const float* __restrict__ sc2, float* __restrict__ out)
{
    __shared__ BoxSmem sm;
    int tile = blockIdx.x, k = blockIdx.y, b = blockIdx.z;
    fill_D(sm, II, tile, k, b, xmin, xmax, ymin, ymax);

    float scale = sc2[k], shift = sc2[C + k];
    size_t base = ((size_t)(b * C + k)) * HW + (size_t)tile * TY * W;
    for (int o = threadIdx.x; o < TY * W; o += 256) {
        int ty = o / W, xx = o % W;
        float v = eval_D(sm, ty, xx);
        size_t idx = base + (size_t)ty * W + xx;
        out[idx] = fmaxf(x[idx] + fmaf(scale, v, shift), 0.f);
    }
}

// ---------------- launch ----------------
extern "C" void kernel_launch(void* const* d_in, const int* in_sizes, int n_in,
                              void* d_out, int out_size, void* d_ws, size_t ws_size,
                              hipStream_t stream)
{
    const float* x    = (const float*)d_in[0];
    const float* w1   = (const float*)d_in[1];
    const float* g1   = (const float*)d_in[2];
    const float* b1   = (const float*)d_in[3];
    const float* xmin = (const float*)d_in[4];
    const float* xmax = (const float*)d_in[5];
    const float* ymin = (const float*)d_in[6];
    const float* ymax = (const float*)d_in[7];
    const float* g2   = (const float*)d_in[8];
    const float* b2   = (const float*)d_in[9];
    float* out = (float*)d_out;

    // ws layout:
    //   [0,256)      sc1: BN1 scale[32] | shift[32]
    //   [256,1280)   sc2: BN2 scale[128]| shift[128]
    //   [4096, +13107200)  h   (B*CM*HW floats)
    //   [+13107200, end)   II  (B*CM*PLANE floats)
    // part1 (64*800 floats = 204.8 KB) aliases start of II (dead before k_scan_part).
    // part2 (256*40 floats = 41 KB) aliases start of h (h dead after k_scan_part).
    char* ws = (char*)d_ws;
    float* sc1 = (float*)ws;
    float* sc2 = (float*)(ws + 256);
    float* h   = (float*)(ws + 4096);
    float* II  = (float*)(ws + 4096 + (size_t)B * CM * HW * sizeof(float));
    float* part1 = II;
    float* part2 = h;

    k_conv     <<<dim3(K1B), 256, 0, stream>>>(x, w1, h, part1);
    k_reduce1  <<<dim3(1), 256, 0, stream>>>(part1, g1, b1, sc1);
    k_scan_part<<<dim3(B * CM * 4), 256, 0, stream>>>(h, sc1, II);
    k_scan_fix <<<dim3(B * CM), 256, 0, stream>>>(II);
    k_box_part <<<dim3(NTILE, C, B), 256, 0, stream>>>(II, xmin, xmax, ymin, ymax, part2);
    k_reduce2  <<<dim3(1), 256, 0, stream>>>(part2, g2, b2, sc2);
    k_box_final<<<dim3(NTILE, C, B), 256, 0, stream>>>(II, x, xmin, xmax, ymin, ymax,
                                                       sc2, out);
}

// Round 6
// 138.856 us; speedup vs baseline: 1.1537x; 1.0388x over previous
//
#include <hip/hip_runtime.h>
#include <cstdint>

constexpr int B  = 4;
constexpr int C  = 128;
constexpr int CM = 32;        // mid channels
constexpr int H  = 160;
constexpr int W  = 160;
constexpr int HW = H * W;     // 25600
constexpr int HP = H + 1;     // 161
constexpr int WP = W + 1;     // 161
constexpr int PLANE = HP * WP; // 25921
constexpr int TY = 16;         // rows per box tile
constexpr int NTILE = H / TY;  // 10
constexpr int K1B = 800;       // K1 grid size
constexpr int NB2 = B * NTILE; // 40 partials per out-channel
constexpr int QR = 40;         // rows per scan quarter

// ------- K1: 1x1 conv, wave = 8 outs x 128 pos, double-buffered prefetch -------
__global__ __launch_bounds__(256) void k_conv(
    const float* __restrict__ x, const float* __restrict__ w1,
    float* __restrict__ h, float* __restrict__ part1)
{
    __shared__ float wT[C * CM];   // wT[c*CM + o]
    int tid = threadIdx.x;
    for (int i = tid; i < C * CM; i += 256) {
        int o = i & (CM - 1), c = i >> 5;
        wT[i] = w1[o * C + c];
    }
    __syncthreads();

    int wave = tid >> 6, lane = tid & 63;
    int bid = blockIdx.x;                 // 800 blocks; 200 per batch image
    int b = bid / 200;
    int p = (bid % 200) * 128 + lane * 2; // float2 per lane
    const float* xb = x + (size_t)b * C * HW + p;

    float2 acc[8];
    #pragma unroll
    for (int j = 0; j < 8; ++j) acc[j] = make_float2(0.f, 0.f);

    const float* wbase = &wT[wave * 8];   // this wave's 8 output channels

    float2 buf0[8], buf1[8];
    #pragma unroll
    for (int u = 0; u < 8; ++u)
        buf0[u] = *reinterpret_cast<const float2*>(xb + (size_t)u * HW);

    auto fma8 = [&](float2 (&bf)[8], int cbase) {
        #pragma unroll
        for (int u = 0; u < 8; ++u) {
            const float4* wr = reinterpret_cast<const float4*>(wbase + (cbase + u) * CM);
            float4 wa = wr[0], wb4 = wr[1];
            float wv[8] = {wa.x, wa.y, wa.z, wa.w, wb4.x, wb4.y, wb4.z, wb4.w};
            #pragma unroll
            for (int j = 0; j < 8; ++j) {
                acc[j].x = fmaf(wv[j], bf[u].x, acc[j].x);
                acc[j].y = fmaf(wv[j], bf[u].y, acc[j].y);
            }
        }
    };

    #pragma unroll 1
    for (int c0 = 0; c0 < C; c0 += 16) {
        #pragma unroll
        for (int u = 0; u < 8; ++u)
            buf1[u] = *reinterpret_cast<const float2*>(xb + (size_t)(c0 + 8 + u) * HW);
        fma8(buf0, c0);
        if (c0 + 16 < C) {
            #pragma unroll
            for (int u = 0; u < 8; ++u)
                buf0[u] = *reinterpret_cast<const float2*>(xb + (size_t)(c0 + 16 + u) * HW);
        }
        fma8(buf1, c0 + 8);
    }

    float* hb = h + ((size_t)(b * CM + wave * 8)) * HW + p;
    #pragma unroll
    for (int j = 0; j < 8; ++j) {
        *reinterpret_cast<float2*>(hb + (size_t)j * HW) = acc[j];
        float s  = acc[j].x + acc[j].y;
        float s2 = acc[j].x * acc[j].x + acc[j].y * acc[j].y;
        #pragma unroll
        for (int off = 32; off > 0; off >>= 1) {
            s  += __shfl_down(s,  off);
            s2 += __shfl_down(s2, off);
        }
        if (lane == 0) {
            int o = wave * 8 + j;
            part1[(size_t)o * K1B + bid]        = s;   // row o      : sums
            part1[(size_t)(o + CM) * K1B + bid] = s2;  // row CM + o : sumsq
        }
    }
}

// ---------------- R1: deterministic reduction -> BN1 scale/shift ----------------
__global__ __launch_bounds__(256) void k_reduce1(
    const float* __restrict__ part1, const float* __restrict__ g1,
    const float* __restrict__ b1, float* __restrict__ sc1)
{
    __shared__ double pr[256];
    __shared__ double dsum[2 * CM];
    int t = threadIdx.x;
    int row = t >> 2, j = t & 3;        // 64 rows x 4 threads
    double acc = 0.0;
    for (int i = j; i < K1B; i += 4) acc += (double)part1[(size_t)row * K1B + i];
    pr[t] = acc;
    __syncthreads();
    if (j == 0) dsum[row] = pr[t] + pr[t + 1] + pr[t + 2] + pr[t + 3];
    __syncthreads();
    if (t < CM) {
        double n = (double)(B * HW);
        double mean = dsum[t] / n;
        double var  = dsum[CM + t] / n - mean * mean;
        float inv   = (float)(1.0 / sqrt(var + 1e-5));
        float scale = g1[t] * inv;
        sc1[t]      = scale;
        sc1[CM + t] = b1[t] - (float)mean * scale;
    }
}

// ------- K2a: BN1+ReLU + row scan + LOCAL col scan per (plane, quarter) -------
//         also emits pre-fix local last row to qlast[plane][q] for q < 3
__global__ __launch_bounds__(256) void k_scan_part(
    const float* __restrict__ h, const float* __restrict__ sc1,
    float* __restrict__ II, float* __restrict__ qlast)
{
    __shared__ float buf[QR * W];   // 40 row-scanned rows, 25600 B
    int tid = threadIdx.x;
    int wave = tid >> 6, lane = tid & 63;
    int blk = blockIdx.x;           // plane*4 + q
    int plane = blk >> 2, q = blk & 3;
    int cm = plane & (CM - 1);

    float scale = sc1[cm];
    float shift = sc1[CM + cm];

    const float* hp = h + (size_t)plane * HW + (size_t)q * QR * W;
    float* IIp = II + (size_t)plane * PLANE;

    // top border row (quarter 0 only) — independent of buf
    if (q == 0) {
        for (int e = tid; e < WP; e += 256) IIp[e] = 0.f;
    }

    // phase 1: BN+ReLU + row inclusive scan into LDS (wave-per-row shuffle scan)
    for (int y = wave; y < QR; y += 4) {
        const float* hr = hp + (size_t)y * W;
        float carry = 0.f;
        #pragma unroll
        for (int x0 = 0; x0 < W; x0 += 64) {
            int xx = x0 + lane;
            float v = (xx < W) ? fmaxf(fmaf(scale, hr[xx], shift), 0.f) : 0.f;
            #pragma unroll
            for (int off = 1; off < 64; off <<= 1) {
                float t = __shfl_up(v, off);
                if (lane >= off) v += t;
            }
            v += carry;
            if (xx < W) buf[y * W + xx] = v;
            carry = __shfl(v, 63);
        }
    }
    __syncthreads();

    // phase 2: local column scan + write II rows q*40+1 .. q*40+40
    float* op = IIp + (size_t)(q * QR + 1) * WP;
    float* ql = qlast + ((size_t)plane * 3 + q) * WP;
    if (tid <= W) {
        float run = 0.f;
        #pragma unroll 4
        for (int r = 0; r < QR; ++r) {
            float v = 0.f;
            if (tid > 0) { run += buf[r * W + (tid - 1)]; v = run; }
            op[(size_t)r * WP + tid] = v;
            if (r == QR - 1 && q < 3) ql[tid] = v;
        }
    }
}

// ------- K2b: add cross-quarter offsets; block = (plane, chunk f of rows 41+40f..80+40f) -------
__global__ __launch_bounds__(256) void k_scan_fix(
    float* __restrict__ II, const float* __restrict__ qlast)
{
    __shared__ float off[WP];
    int tid = threadIdx.x;
    int blk = blockIdx.x;
    int plane = blk / 3, f = blk % 3;

    const float* qb = qlast + (size_t)plane * 3 * WP;
    for (int v = tid; v < WP; v += 256) {
        float s = qb[v];
        if (f >= 1) s += qb[WP + v];
        if (f >= 2) s += qb[2 * WP + v];
        off[v] = s;
    }
    __syncthreads();

    float* P = II + (size_t)plane * PLANE + (size_t)(41 + f * QR) * WP;
    constexpr int total = QR * WP;
    for (int e = tid; e < total; e += 256) {
        P[e] += off[e % WP];
    }
}

// ---------------- box tile machinery ----------------
struct BoxSmem {
    float D[TY][WP];      // row-interp difference rows
    int   ru0[2][TY];     // [0]=lo, [1]=hi row coords
    int   ru1[2][TY];
    float rua[2][TY];
    int   cv0[2][W];      // col coords ([0]=lo, [1]=hi)
    float cva[2][W];
};

__device__ inline void fill_D(BoxSmem& sm, const float* __restrict__ II,
    int tile, int k, int b,
    const float* __restrict__ xmin, const float* __restrict__ xmax,
    const float* __restrict__ ymin, const float* __restrict__ ymax)
{
    int tid = threadIdx.x;
    if (tid < 2 * TY) {
        int side = tid / TY, ty = tid % TY;
        float off = side ? (xmax[k] + 1.f) : xmin[k];
        float u = fminf(fmaxf((float)(tile * TY + ty) + off, 0.f), 160.f);
        float uf = floorf(u);
        int i0 = (int)uf;
        sm.ru0[side][ty] = i0;
        sm.ru1[side][ty] = min(i0 + 1, 160);
        sm.rua[side][ty] = u - uf;
    }
    for (int e = tid; e < 2 * W; e += 256) {
        int side = e / W, xx = e % W;
        float off = side ? (ymax[k] + 1.f) : ymin[k];
        float v = fminf(fmaxf((float)xx + off, 0.f), 160.f);
        float vf = floorf(v);
        sm.cv0[side][xx] = (int)vf;
        sm.cva[side][xx] = v - vf;
    }
    __syncthreads();

    const float* P = II + (size_t)(b * CM + (k >> 2)) * PLANE;
    for (int e = tid; e < TY * WP; e += 256) {
        int ty = e / WP, v = e % WP;
        float al = sm.rua[0][ty], ah = sm.rua[1][ty];
        float lo = P[(size_t)sm.ru0[0][ty] * WP + v] * (1.f - al)
                 + P[(size_t)sm.ru1[0][ty] * WP + v] * al;
        float hi = P[(size_t)sm.ru0[1][ty] * WP + v] * (1.f - ah)
                 + P[(size_t)sm.ru1[1][ty] * WP + v] * ah;
        sm.D[ty][v] = hi - lo;
    }
    __syncthreads();
}

__device__ inline float eval_D(const BoxSmem& sm, int ty, int xx)
{
    int   l0 = sm.cv0[0][xx];
    float la = sm.cva[0][xx];
    int   l1 = min(l0 + 1, 160);
    int   h0 = sm.cv0[1][xx];
    float ha = sm.cva[1][xx];
    int   h1 = min(h0 + 1, 160);
    const float* Dr = sm.D[ty];
    return (Dr[h0] * (1.f - ha) + Dr[h1] * ha)
         - (Dr[l0] * (1.f - la) + Dr[l1] * la);
}

// ---------------- K4: box conv -> BN2 partial stats ----------------
__global__ __launch_bounds__(256) void k_box_part(
    const float* __restrict__ II,
    const float* __restrict__ xmin, const float* __restrict__ xmax,
    const float* __restrict__ ymin, const float* __restrict__ ymax,
    float* __restrict__ part2)
{
    __shared__ BoxSmem sm;
    __shared__ float red[4][2];
    int tile = blockIdx.x, k = blockIdx.y, b = blockIdx.z;
    fill_D(sm, II, tile, k, b, xmin, xmax, ymin, ymax);

    float s = 0.f, s2 = 0.f;
    for (int o = threadIdx.x; o < TY * W; o += 256) {
        int ty = o / W, xx = o % W;
        float v = eval_D(sm, ty, xx);
        s  += v;
        s2 += v * v;
    }
    #pragma unroll
    for (int off = 32; off > 0; off >>= 1) {
        s  += __shfl_down(s,  off);
        s2 += __shfl_down(s2, off);
    }
    int wave = threadIdx.x >> 6, lane = threadIdx.x & 63;
    if (lane == 0) { red[wave][0] = s; red[wave][1] = s2; }
    __syncthreads();
    if (threadIdx.x == 0) {
        int idx = b * NTILE + tile;     // 0..39
        part2[(size_t)k * NB2 + idx]       = red[0][0] + red[1][0] + red[2][0] + red[3][0];
        part2[(size_t)(C + k) * NB2 + idx] = red[0][1] + red[1][1] + red[2][1] + red[3][1];
    }
}

// ---------------- R2: deterministic reduction -> BN2 scale/shift ----------------
__global__ __launch_bounds__(256) void k_reduce2(
    const float* __restrict__ part2, const float* __restrict__ g2,
    const float* __restrict__ b2, float* __restrict__ sc2)
{
    __shared__ double dsum[2 * C];
    int t = threadIdx.x;                 // 256 rows, one per thread
    double acc = 0.0;
    for (int i = 0; i < NB2; ++i) acc += (double)part2[(size_t)t * NB2 + i];
    dsum[t] = acc;
    __syncthreads();
    if (t < C) {
        double n = (double)(B * HW);
        double mean = dsum[t] / n;
        double var  = dsum[C + t] / n - mean * mean;
        float inv   = (float)(1.0 / sqrt(var + 1e-5));
        float scale = g2[t] * inv;
        sc2[t]     = scale;
        sc2[C + t] = b2[t] - (float)mean * scale;
    }
}

// ---------------- K5: box conv again, BN2, relu(x + h) ----------------
__global__ __launch_bounds__(256) void k_box_final(
    const float* __restrict__ II, const float* __restrict__ x,
    const float* __restrict__ xmin, const float* __restrict__ xmax,
    const float* __restrict__ ymin, const float* __restrict__ ymax,
    const float* __restrict__ sc2, float* __restrict__ out)
{
    __shared__ BoxSmem sm;
    int tile = blockIdx.x, k = blockIdx.y, b = blockIdx.z;
    fill_D(sm, II, tile, k, b, xmin, xmax, ymin, ymax);

    float scale = sc2[k], shift = sc2[C + k];
    size_t base = ((size_t)(b * C + k)) * HW + (size_t)tile * TY * W;
    for (int o = threadIdx.x; o < TY * W; o += 256) {
        int ty = o / W, xx = o % W;
        float v = eval_D(sm, ty, xx);
        size_t idx = base + (size_t)ty * W + xx;
        out[idx] = fmaxf(x[idx] + fmaf(scale, v, shift), 0.f);
    }
}

// ---------------- launch ----------------
extern "C" void kernel_launch(void* const* d_in, const int* in_sizes, int n_in,
                              void* d_out, int out_size, void* d_ws, size_t ws_size,
                              hipStream_t stream)
{
    const float* x    = (const float*)d_in[0];
    const float* w1   = (const float*)d_in[1];
    const float* g1   = (const float*)d_in[2];
    const float* b1   = (const float*)d_in[3];
    const float* xmin = (const float*)d_in[4];
    const float* xmax = (const float*)d_in[5];
    const float* ymin = (const float*)d_in[6];
    const float* ymax = (const float*)d_in[7];
    const float* g2   = (const float*)d_in[8];
    const float* b2   = (const float*)d_in[9];
    float* out = (float*)d_out;

    // ws layout:
    //   [0,256)      sc1: BN1 scale[32] | shift[32]
    //   [256,1280)   sc2: BN2 scale[128]| shift[128]
    //   [4096, +13107200)       h   (B*CM*HW floats)
    //   [+13107200, +26379052)  II  (B*CM*PLANE floats)
    //   [26382848, +247296)     qlast (B*CM*3*WP floats)
    // part1 (64*800 floats) aliases start of II (dead before k_scan_part).
    // part2 (256*40 floats) aliases start of h (h dead after k_scan_part).
    char* ws = (char*)d_ws;
    float* sc1 = (float*)ws;
    float* sc2 = (float*)(ws + 256);
    float* h   = (float*)(ws + 4096);
    float* II  = (float*)(ws + 4096 + (size_t)B * CM * HW * sizeof(float));
    float* qlast = (float*)(ws + 4096 + (size_t)B * CM * HW * sizeof(float)
                               + (size_t)B * CM * PLANE * sizeof(float));
    float* part1 = II;
    float* part2 = h;

    k_conv     <<<dim3(K1B), 256, 0, stream>>>(x, w1, h, part1);
    k_reduce1  <<<dim3(1), 256, 0, stream>>>(part1, g1, b1, sc1);
    k_scan_part<<<dim3(B * CM * 4), 256, 0, stream>>>(h, sc1, II, qlast);
    k_scan_fix <<<dim3(B * CM * 3), 256, 0, stream>>>(II, qlast);
    k_box_part <<<dim3(NTILE, C, B), 256, 0, stream>>>(II, xmin, xmax, ymin, ymax, part2);
    k_reduce2  <<<dim3(1), 256, 0, stream>>>(part2, g2, b2, sc2);
    k_box_final<<<dim3(NTILE, C, B), 256, 0, stream>>>(II, x, xmin, xmax, ymin, ymax,
                                                       sc2, out);
}